// Round 1
// baseline (4765.601 us; speedup 1.0000x reference)
//
#include <hip/hip_runtime.h>

#define NB 2
#define NH 16
#define SEQ 2048
#define DMODEL 1024
#define DHEAD 64

// ---- bf16 <-> f32 helpers (bit-level, RNE; no dependency on hip_bf16 types) ----
static __device__ __forceinline__ unsigned short f2bf(float f) {
    unsigned int u = __float_as_uint(f);
    u += 0x7fffu + ((u >> 16) & 1u);   // round-to-nearest-even
    return (unsigned short)(u >> 16);
}
static __device__ __forceinline__ float bf2f(unsigned short s) {
    return __uint_as_float(((unsigned int)s) << 16);
}

// =====================================================================
// Kernel 1: per-head projections  qh/kh/vh[b,h,s,e] = X[b,s,:] @ W[h,:,e]
// grid (SEQ/64, NB*NH, 3), block 256.  fp32 in, bf16 out.
// =====================================================================
__global__ __launch_bounds__(256) void proj_kernel(
    const float* __restrict__ q, const float* __restrict__ k, const float* __restrict__ v,
    const float* __restrict__ Wq, const float* __restrict__ Wk, const float* __restrict__ Wv,
    unsigned short* __restrict__ qh, unsigned short* __restrict__ kh, unsigned short* __restrict__ vh)
{
    const int t  = threadIdx.x;
    const int tx = t & 15, ty = t >> 4;
    const int row0 = blockIdx.x * 64;
    const int bh = blockIdx.y;
    const int b = bh >> 4, h = bh & 15;
    const int typ = blockIdx.z;

    const float* X = (typ == 0) ? q  : (typ == 1) ? k  : v;
    const float* W = (typ == 0) ? Wq : (typ == 1) ? Wk : Wv;
    unsigned short* Y = (typ == 0) ? qh : (typ == 1) ? kh : vh;

    __shared__ __align__(16) float Xt[32][68];   // [kk][row]  (transposed X tile)
    __shared__ __align__(16) float Ws[32][64];   // [kk][col]

    const float* Xbase = X + ((size_t)b * SEQ + row0) * DMODEL;
    const float* Wbase = W + (size_t)h * DMODEL * DHEAD;

    float acc[4][4] = {};

    for (int k0 = 0; k0 < DMODEL; k0 += 32) {
        const int idx = t * 2;
        #pragma unroll
        for (int u = 0; u < 2; ++u) {
            const int id = idx + u;
            // X tile: 64 rows x 32 k  -> transposed into Xt
            const int r = id >> 3, c4 = id & 7;
            float4 xv = *(const float4*)(Xbase + (size_t)r * DMODEL + k0 + c4 * 4);
            Xt[c4*4+0][r] = xv.x;
            Xt[c4*4+1][r] = xv.y;
            Xt[c4*4+2][r] = xv.z;
            Xt[c4*4+3][r] = xv.w;
            // W tile: 32 k x 64 cols
            const int r2 = id >> 4, c42 = id & 15;
            *(float4*)&Ws[r2][c42*4] = *(const float4*)(Wbase + (size_t)(k0 + r2) * DHEAD + c42 * 4);
        }
        __syncthreads();
        #pragma unroll
        for (int kk = 0; kk < 32; ++kk) {
            float4 a4 = *(const float4*)&Xt[kk][ty*4];
            float4 b4 = *(const float4*)&Ws[kk][tx*4];
            const float a[4]  = {a4.x, a4.y, a4.z, a4.w};
            const float bb[4] = {b4.x, b4.y, b4.z, b4.w};
            #pragma unroll
            for (int i = 0; i < 4; ++i)
                #pragma unroll
                for (int j = 0; j < 4; ++j)
                    acc[i][j] = fmaf(a[i], bb[j], acc[i][j]);
        }
        __syncthreads();
    }

    unsigned short* Ybase = Y + ((size_t)bh * SEQ + row0) * DHEAD;
    #pragma unroll
    for (int i = 0; i < 4; ++i) {
        ushort4 st;
        st.x = f2bf(acc[i][0]); st.y = f2bf(acc[i][1]);
        st.z = f2bf(acc[i][2]); st.w = f2bf(acc[i][3]);
        *(ushort4*)(Ybase + (size_t)(ty*4+i) * DHEAD + tx*4) = st;
    }
}

// =====================================================================
// Kernel 2: flash attention per (b,h), 64-row Q tile per block.
// grid (SEQ/64, NB*NH), block 256.  mask!=0 => -inf (masked out).
// Writes att in head-concat layout: att[b, s, h*64+e]  (bf16)
// =====================================================================
__global__ __launch_bounds__(256) void attn_kernel(
    const unsigned short* __restrict__ qh, const unsigned short* __restrict__ kh,
    const unsigned short* __restrict__ vh, const int* __restrict__ mask,
    unsigned short* __restrict__ att)
{
    const int t  = threadIdx.x;
    const int tx = t & 15, ty = t >> 4;
    const int row0 = blockIdx.x * 64;
    const int bh = blockIdx.y;
    const int b = bh >> 4, h = bh & 15;

    __shared__ __align__(16) float Qt[64][68];  // [d][q]
    __shared__ __align__(16) float Kt[64][68];  // [d][k]; reused as Pt[k][q]
    __shared__ __align__(16) float Vs[64][68];  // [k][e]

    const unsigned short* Qbase = qh + ((size_t)bh * SEQ + row0) * DHEAD;
    const unsigned short* Kbase = kh + (size_t)bh * SEQ * DHEAD;
    const unsigned short* Vbase = vh + (size_t)bh * SEQ * DHEAD;
    const int* Mbase = mask + ((size_t)b * SEQ + row0) * (size_t)SEQ;

    // stage Q (transposed)
    {
        const int idx = t * 4;
        #pragma unroll
        for (int u = 0; u < 4; ++u) {
            const int id = idx + u;
            const int r = id >> 4, c4 = id & 15;
            ushort4 qv = *(const ushort4*)(Qbase + (size_t)r * DHEAD + c4 * 4);
            Qt[c4*4+0][r] = bf2f(qv.x);
            Qt[c4*4+1][r] = bf2f(qv.y);
            Qt[c4*4+2][r] = bf2f(qv.z);
            Qt[c4*4+3][r] = bf2f(qv.w);
        }
    }

    float O[4][4] = {};
    float m_i[4], l_i[4];
    #pragma unroll
    for (int i = 0; i < 4; ++i) { m_i[i] = -1e30f; l_i[i] = 0.0f; }

    for (int kt = 0; kt < SEQ; kt += 64) {
        // stage K (transposed) and V (straight)
        {
            const int idx = t * 4;
            #pragma unroll
            for (int u = 0; u < 4; ++u) {
                const int id = idx + u;
                const int r = id >> 4, c4 = id & 15;
                ushort4 kv = *(const ushort4*)(Kbase + (size_t)(kt + r) * DHEAD + c4 * 4);
                Kt[c4*4+0][r] = bf2f(kv.x);
                Kt[c4*4+1][r] = bf2f(kv.y);
                Kt[c4*4+2][r] = bf2f(kv.z);
                Kt[c4*4+3][r] = bf2f(kv.w);
                ushort4 vv = *(const ushort4*)(Vbase + (size_t)(kt + r) * DHEAD + c4 * 4);
                float4 vf = make_float4(bf2f(vv.x), bf2f(vv.y), bf2f(vv.z), bf2f(vv.w));
                *(float4*)&Vs[r][c4*4] = vf;
            }
        }
        __syncthreads();

        // S = Q K^T   (q = 4ty+i, k = 4tx+j)
        float s[4][4] = {};
        #pragma unroll
        for (int d = 0; d < 64; ++d) {
            float4 a4 = *(const float4*)&Qt[d][ty*4];
            float4 b4 = *(const float4*)&Kt[d][tx*4];
            const float a[4]  = {a4.x, a4.y, a4.z, a4.w};
            const float bb[4] = {b4.x, b4.y, b4.z, b4.w};
            #pragma unroll
            for (int i = 0; i < 4; ++i)
                #pragma unroll
                for (int j = 0; j < 4; ++j)
                    s[i][j] = fmaf(a[i], bb[j], s[i][j]);
        }

        // mask + scale + online softmax (row stats across the 16 tx lanes)
        float p[4][4], alpha[4], rs_[4], mnew[4];
        #pragma unroll
        for (int i = 0; i < 4; ++i) {
            const int4 mk = *(const int4*)(Mbase + (size_t)(ty*4+i) * SEQ + kt + tx*4);
            float v0 = mk.x ? -1e30f : s[i][0] * 0.125f;
            float v1 = mk.y ? -1e30f : s[i][1] * 0.125f;
            float v2 = mk.z ? -1e30f : s[i][2] * 0.125f;
            float v3 = mk.w ? -1e30f : s[i][3] * 0.125f;
            float rm = fmaxf(fmaxf(v0, v1), fmaxf(v2, v3));
            rm = fmaxf(rm, __shfl_xor(rm, 1, 64));
            rm = fmaxf(rm, __shfl_xor(rm, 2, 64));
            rm = fmaxf(rm, __shfl_xor(rm, 4, 64));
            rm = fmaxf(rm, __shfl_xor(rm, 8, 64));
            const float mn = fmaxf(m_i[i], rm);
            mnew[i]  = mn;
            alpha[i] = __expf(m_i[i] - mn);
            p[i][0] = mk.x ? 0.0f : __expf(v0 - mn);
            p[i][1] = mk.y ? 0.0f : __expf(v1 - mn);
            p[i][2] = mk.z ? 0.0f : __expf(v2 - mn);
            p[i][3] = mk.w ? 0.0f : __expf(v3 - mn);
            float sm = (p[i][0] + p[i][1]) + (p[i][2] + p[i][3]);
            sm += __shfl_xor(sm, 1, 64);
            sm += __shfl_xor(sm, 2, 64);
            sm += __shfl_xor(sm, 4, 64);
            sm += __shfl_xor(sm, 8, 64);
            rs_[i] = sm;
        }
        #pragma unroll
        for (int i = 0; i < 4; ++i) {
            l_i[i] = l_i[i] * alpha[i] + rs_[i];
            m_i[i] = mnew[i];
            #pragma unroll
            for (int j = 0; j < 4; ++j) O[i][j] *= alpha[i];
        }

        __syncthreads();   // all S-phase reads of Kt finished
        // write P transposed into Kt storage: Pt[k][q]
        #pragma unroll
        for (int i = 0; i < 4; ++i)
            #pragma unroll
            for (int j = 0; j < 4; ++j)
                Kt[tx*4+j][ty*4+i] = p[i][j];
        __syncthreads();

        // O += P @ V   (q = 4ty+i, e = 4tx+j)
        #pragma unroll
        for (int kk = 0; kk < 64; ++kk) {
            float4 pa = *(const float4*)&Kt[kk][ty*4];
            float4 vv = *(const float4*)&Vs[kk][tx*4];
            const float a[4]  = {pa.x, pa.y, pa.z, pa.w};
            const float bb[4] = {vv.x, vv.y, vv.z, vv.w};
            #pragma unroll
            for (int i = 0; i < 4; ++i)
                #pragma unroll
                for (int j = 0; j < 4; ++j)
                    O[i][j] = fmaf(a[i], bb[j], O[i][j]);
        }
        __syncthreads();
    }

    // epilogue: normalize and store in head-concat layout
    unsigned short* Obase = att + ((size_t)b * SEQ + row0) * (NH * DHEAD) + h * DHEAD;
    #pragma unroll
    for (int i = 0; i < 4; ++i) {
        const float inv = 1.0f / l_i[i];
        ushort4 st;
        st.x = f2bf(O[i][0] * inv);
        st.y = f2bf(O[i][1] * inv);
        st.z = f2bf(O[i][2] * inv);
        st.w = f2bf(O[i][3] * inv);
        *(ushort4*)(Obase + (size_t)(ty*4+i) * (NH * DHEAD) + tx*4) = st;
    }
}

// =====================================================================
// Kernel 3: output projection  out[r, j] = att[r, :] @ Wo[:, j]
// grid (DMODEL/64, NB*SEQ/64), block 256.  bf16 att, f32 Wo, f32 out.
// =====================================================================
__global__ __launch_bounds__(256) void out_proj_kernel(
    const unsigned short* __restrict__ att, const float* __restrict__ Wo,
    float* __restrict__ out)
{
    const int t  = threadIdx.x;
    const int tx = t & 15, ty = t >> 4;
    const int col0 = blockIdx.x * 64;
    const int row0 = blockIdx.y * 64;

    __shared__ __align__(16) float Xt[32][68];   // [kk][row]
    __shared__ __align__(16) float Ws[32][64];   // [kk][col]

    float acc[4][4] = {};

    for (int k0 = 0; k0 < DMODEL; k0 += 32) {
        const int idx = t * 2;
        #pragma unroll
        for (int u = 0; u < 2; ++u) {
            const int id = idx + u;
            const int r = id >> 3, c4 = id & 7;
            ushort4 xv = *(const ushort4*)(att + (size_t)(row0 + r) * DMODEL + k0 + c4 * 4);
            Xt[c4*4+0][r] = bf2f(xv.x);
            Xt[c4*4+1][r] = bf2f(xv.y);
            Xt[c4*4+2][r] = bf2f(xv.z);
            Xt[c4*4+3][r] = bf2f(xv.w);
            const int r2 = id >> 4, c42 = id & 15;
            *(float4*)&Ws[r2][c42*4] = *(const float4*)(Wo + (size_t)(k0 + r2) * DMODEL + col0 + c42 * 4);
        }
        __syncthreads();
        #pragma unroll
        for (int kk = 0; kk < 32; ++kk) {
            float4 a4 = *(const float4*)&Xt[kk][ty*4];
            float4 b4 = *(const float4*)&Ws[kk][tx*4];
            const float a[4]  = {a4.x, a4.y, a4.z, a4.w};
            const float bb[4] = {b4.x, b4.y, b4.z, b4.w};
            #pragma unroll
            for (int i = 0; i < 4; ++i)
                #pragma unroll
                for (int j = 0; j < 4; ++j)
                    acc[i][j] = fmaf(a[i], bb[j], acc[i][j]);
        }
        __syncthreads();
    }

    #pragma unroll
    for (int i = 0; i < 4; ++i) {
        float4 o4 = make_float4(acc[i][0], acc[i][1], acc[i][2], acc[i][3]);
        *(float4*)(out + (size_t)(row0 + ty*4 + i) * DMODEL + col0 + tx*4) = o4;
    }
}

extern "C" void kernel_launch(void* const* d_in, const int* in_sizes, int n_in,
                              void* d_out, int out_size, void* d_ws, size_t ws_size,
                              hipStream_t stream) {
    const float* q    = (const float*)d_in[0];
    const float* k    = (const float*)d_in[1];
    const float* v    = (const float*)d_in[2];
    const int*   mask = (const int*)  d_in[3];   // bool marshalled as int32
    const float* Wq   = (const float*)d_in[4];
    const float* Wk   = (const float*)d_in[5];
    const float* Wv   = (const float*)d_in[6];
    const float* Wo   = (const float*)d_in[7];
    float* out = (float*)d_out;

    // workspace layout (bf16): qh | kh | vh | att   (4 x 4,194,304 elems = 33.5 MB)
    unsigned short* ws  = (unsigned short*)d_ws;
    const size_t    n1  = (size_t)NB * NH * SEQ * DHEAD;   // 4,194,304
    unsigned short* qh  = ws;
    unsigned short* kh  = ws + n1;
    unsigned short* vh  = ws + 2 * n1;
    unsigned short* att = ws + 3 * n1;

    proj_kernel<<<dim3(SEQ / 64, NB * NH, 3), 256, 0, stream>>>(q, k, v, Wq, Wk, Wv, qh, kh, vh);
    attn_kernel<<<dim3(SEQ / 64, NB * NH), 256, 0, stream>>>(qh, kh, vh, mask, att);
    out_proj_kernel<<<dim3(DMODEL / 64, (NB * SEQ) / 64), 256, 0, stream>>>(att, Wo, out);
}

// Round 2
// 478.596 us; speedup vs baseline: 9.9575x; 9.9575x over previous
//
#include <hip/hip_runtime.h>

#define NB 2
#define NH 16
#define SEQ 2048
#define DMODEL 1024
#define DHEAD 64

typedef __attribute__((ext_vector_type(8))) short bf16x8;
typedef __attribute__((ext_vector_type(4))) float f32x4;

static __device__ __forceinline__ unsigned short f2bf(float f) {
    unsigned int u = __float_as_uint(f);
    u += 0x7fffu + ((u >> 16) & 1u);   // RNE
    return (unsigned short)(u >> 16);
}
static __device__ __forceinline__ unsigned int pk2(float lo, float hi) {
    return (unsigned int)f2bf(lo) | ((unsigned int)f2bf(hi) << 16);
}
static __device__ __forceinline__ void gld_lds16(const unsigned short* g, unsigned short* l) {
    __builtin_amdgcn_global_load_lds(
        (const __attribute__((address_space(1))) unsigned int*)g,
        (__attribute__((address_space(3))) unsigned int*)l, 16, 0, 0);
}

// =====================================================================
// Prep A: pack bool mask (int32) into 64-bit words: bit l of word w for
// row (b,s) = mask[b][s][w*64+l] != 0.  One wave per (b,s) row.
// =====================================================================
__global__ __launch_bounds__(256) void pack_mask_kernel(
    const int* __restrict__ mask, unsigned long long* __restrict__ mpack)
{
    const int wave = blockIdx.x * 4 + (threadIdx.x >> 6);  // 0..4095 = b*2048+s
    const int lane = threadIdx.x & 63;
    const int* row = mask + (size_t)wave * SEQ;
    unsigned long long* orow = mpack + (size_t)wave * (SEQ / 64);
    for (int w = 0; w < SEQ / 64; ++w) {
        int m = row[w * 64 + lane];
        unsigned long long bits = __ballot(m != 0);
        if (lane == 0) orow[w] = bits;
    }
}

// =====================================================================
// Prep B: transpose + f32->bf16:  dst[C][R] = bf16(src[R][C]), batched.
// grid (C/64, R/64, batch), block 256.
// =====================================================================
__global__ __launch_bounds__(256) void transpose_cvt_kernel(
    const float* __restrict__ src, unsigned short* __restrict__ dst, int R, int C)
{
    const int tile_c = blockIdx.x * 64, tile_r = blockIdx.y * 64;
    const size_t mat = (size_t)blockIdx.z * R * C;
    __shared__ float Ls[64][65];
    const float* S = src + mat;
    unsigned short* D = dst + mat;
    const int t = threadIdx.x;
    const int c4 = (t & 15) * 4;
    for (int rr = t >> 4; rr < 64; rr += 16) {
        float4 v = *(const float4*)(S + (size_t)(tile_r + rr) * C + tile_c + c4);
        Ls[rr][c4 + 0] = v.x; Ls[rr][c4 + 1] = v.y;
        Ls[rr][c4 + 2] = v.z; Ls[rr][c4 + 3] = v.w;
    }
    __syncthreads();
    const int r4 = (t & 15) * 4;
    for (int cc = t >> 4; cc < 64; cc += 16) {
        ushort4 o;
        o.x = f2bf(Ls[r4 + 0][cc]); o.y = f2bf(Ls[r4 + 1][cc]);
        o.z = f2bf(Ls[r4 + 2][cc]); o.w = f2bf(Ls[r4 + 3][cc]);
        *(ushort4*)(D + (size_t)(tile_c + cc) * R + tile_r + r4) = o;
    }
}

// =====================================================================
// MFMA GEMM: C[4096 x 1024] = A[4096 x 1024] @ Bt^T  (Bt is [1024 n][1024 k] bf16)
// 128x128 tile, BK=64, 4 waves 2x2, XOR-swizzled LDS (chunk c at pos c^(row&7)).
// MODE 0: A = f32 (manual staging w/ convert), C = bf16 head-permuted (proj)
// MODE 1: A = bf16 (global_load_lds),          C = f32 natural     (out-proj)
// =====================================================================
template<int MODE>
__global__ __launch_bounds__(256) void gemm_kernel(
    const void* __restrict__ Ap, const unsigned short* __restrict__ Bt,
    void* __restrict__ Cp)
{
    const int t = threadIdx.x, lane = t & 63, w = t >> 6;
    const int lg = lane >> 4, ln = lane & 15;
    const int wx = w & 1, wy = w >> 1;
    const int m0 = blockIdx.y * 128, n0 = blockIdx.x * 128;

    __shared__ __align__(16) unsigned short As[128 * 64];
    __shared__ __align__(16) unsigned short Bs[128 * 64];

    f32x4 acc[4][4] = {};

    for (int kk = 0; kk < DMODEL; kk += 64) {
        // ---- B tile via global_load_lds (16B, swizzled) ----
        #pragma unroll
        for (int i = 0; i < 4; ++i) {
            int s = (w * 4 + i) * 64 + lane;
            int n = s >> 3, c = (s & 7) ^ (n & 7);
            gld_lds16(Bt + (size_t)(n0 + n) * DMODEL + kk + c * 8, Bs + (size_t)s * 8);
        }
        // ---- A tile ----
        if (MODE == 1) {
            const unsigned short* A = (const unsigned short*)Ap;
            #pragma unroll
            for (int i = 0; i < 4; ++i) {
                int s = (w * 4 + i) * 64 + lane;
                int n = s >> 3, c = (s & 7) ^ (n & 7);
                gld_lds16(A + (size_t)(m0 + n) * DMODEL + kk + c * 8, As + (size_t)s * 8);
            }
        } else {
            const float* A = (const float*)Ap;
            const int row = t >> 1, kh2 = (t & 1) * 32;
            const float* Ag = A + (size_t)(m0 + row) * DMODEL + kk + kh2;
            #pragma unroll
            for (int j = 0; j < 4; ++j) {
                float4 x0 = *(const float4*)(Ag + j * 8);
                float4 x1 = *(const float4*)(Ag + j * 8 + 4);
                uint4 val;
                val.x = pk2(x0.x, x0.y); val.y = pk2(x0.z, x0.w);
                val.z = pk2(x1.x, x1.y); val.w = pk2(x1.z, x1.w);
                int c = (kh2 >> 3) + j;
                *(uint4*)(As + row * 64 + ((c ^ (row & 7)) * 8)) = val;
            }
        }
        __syncthreads();
        #pragma unroll
        for (int ks = 0; ks < 2; ++ks) {
            bf16x8 af[4], bf[4];
            #pragma unroll
            for (int rb = 0; rb < 4; ++rb) {
                int r = wy * 64 + rb * 16 + ln;
                af[rb] = *(const bf16x8*)(As + r * 64 + (((ks * 4 + lg) ^ (r & 7)) * 8));
            }
            #pragma unroll
            for (int nb = 0; nb < 4; ++nb) {
                int n = wx * 64 + nb * 16 + ln;
                bf[nb] = *(const bf16x8*)(Bs + n * 64 + (((ks * 4 + lg) ^ (n & 7)) * 8));
            }
            #pragma unroll
            for (int rb = 0; rb < 4; ++rb)
                #pragma unroll
                for (int nb = 0; nb < 4; ++nb)
                    acc[rb][nb] = __builtin_amdgcn_mfma_f32_16x16x32_bf16(
                        af[rb], bf[nb], acc[rb][nb], 0, 0, 0);
        }
        __syncthreads();
    }

    if (MODE == 0) {
        unsigned short* C = (unsigned short*)Cp;
        #pragma unroll
        for (int rb = 0; rb < 4; ++rb)
            #pragma unroll
            for (int nb = 0; nb < 4; ++nb)
                #pragma unroll
                for (int r = 0; r < 4; ++r) {
                    int grow = m0 + wy * 64 + rb * 16 + lg * 4 + r;   // b*2048+s
                    int gcol = n0 + wx * 64 + nb * 16 + ln;           // h*64+e
                    size_t idx = ((size_t)((grow >> 11) * NH + (gcol >> 6)) * SEQ
                                  + (grow & (SEQ - 1))) * DHEAD + (gcol & 63);
                    C[idx] = f2bf(acc[rb][nb][r]);
                }
    } else {
        float* C = (float*)Cp;
        #pragma unroll
        for (int rb = 0; rb < 4; ++rb)
            #pragma unroll
            for (int nb = 0; nb < 4; ++nb)
                #pragma unroll
                for (int r = 0; r < 4; ++r) {
                    int grow = m0 + wy * 64 + rb * 16 + lg * 4 + r;
                    int gcol = n0 + wx * 64 + nb * 16 + ln;
                    C[(size_t)grow * DMODEL + gcol] = acc[rb][nb][r];
                }
    }
}

// =====================================================================
// MFMA flash attention. grid (SEQ/64, NB*NH), block 256 (4 waves).
// Wave w owns q-rows [row0+16w, row0+16w+16). K-tile = 64 keys.
// Q/K frags direct from global; V transposed through LDS; P via private LDS.
// =====================================================================
__global__ __launch_bounds__(256) void attn_kernel(
    const unsigned short* __restrict__ qh, const unsigned short* __restrict__ kh,
    const unsigned short* __restrict__ vh, const unsigned long long* __restrict__ mpack,
    unsigned short* __restrict__ att)
{
    const int t = threadIdx.x, lane = t & 63, w = t >> 6;
    const int lg = lane >> 4, ln = lane & 15;
    const int row0 = blockIdx.x * 64;
    const int bh = blockIdx.y, b = bh >> 4, h = bh & 15;

    __shared__ __align__(16) unsigned short Vt[64][72];      // [dh][key]
    __shared__ __align__(16) unsigned short Ps[4][16][72];   // per-wave [q][key]

    // Q fragments (A-layout): row = ln, k = dh
    const unsigned short* Qb = qh + ((size_t)bh * SEQ + row0 + w * 16 + ln) * DHEAD;
    bf16x8 qf0 = *(const bf16x8*)(Qb + lg * 8);
    bf16x8 qf1 = *(const bf16x8*)(Qb + 32 + lg * 8);

    f32x4 O[4] = {};
    float m_i[4], l_i[4];
    #pragma unroll
    for (int r = 0; r < 4; ++r) { m_i[r] = -1e30f; l_i[r] = 0.0f; }

    const unsigned short* Kb = kh + (size_t)bh * SEQ * DHEAD;
    const unsigned short* Vb = vh + (size_t)bh * SEQ * DHEAD;
    const unsigned long long* Mb = mpack + ((size_t)b * SEQ + row0 + w * 16) * (SEQ / 64);

    const int vkey = t >> 2, vd = (t & 3) * 16;   // V staging assignment

    for (int kt = 0; kt < SEQ; kt += 64) {
        // ---- V staging reads (coalesced, consumed after barrier) ----
        const unsigned short* vg = Vb + (size_t)(kt + vkey) * DHEAD + vd;
        ushort4 v0 = *(const ushort4*)(vg);
        ushort4 v1 = *(const ushort4*)(vg + 4);
        ushort4 v2 = *(const ushort4*)(vg + 8);
        ushort4 v3 = *(const ushort4*)(vg + 12);

        // ---- S = Q K^T  (B-frags direct from global) ----
        f32x4 S[4] = {};
        #pragma unroll
        for (int kb = 0; kb < 4; ++kb) {
            const unsigned short* kp = Kb + (size_t)(kt + kb * 16 + ln) * DHEAD + lg * 8;
            bf16x8 k0 = *(const bf16x8*)(kp);
            bf16x8 k1 = *(const bf16x8*)(kp + 32);
            S[kb] = __builtin_amdgcn_mfma_f32_16x16x32_bf16(qf0, k0, S[kb], 0, 0, 0);
            S[kb] = __builtin_amdgcn_mfma_f32_16x16x32_bf16(qf1, k1, S[kb], 0, 0, 0);
        }

        // ---- mask + online softmax (rows = lg*4+r, cols = kb*16+ln) ----
        float p[4][4], alpha[4];
        #pragma unroll
        for (int r = 0; r < 4; ++r) {
            unsigned long long mwr = Mb[(size_t)(lg * 4 + r) * (SEQ / 64) + (kt >> 6)];
            float vsc[4]; int msk[4];
            float mx = -1e30f;
            #pragma unroll
            for (int kb = 0; kb < 4; ++kb) {
                msk[kb] = (int)((mwr >> (kb * 16 + ln)) & 1ull);
                float sv = S[kb][r] * 0.125f;
                vsc[kb] = msk[kb] ? -1e30f : sv;
                mx = fmaxf(mx, vsc[kb]);
            }
            mx = fmaxf(mx, __shfl_xor(mx, 1, 64));
            mx = fmaxf(mx, __shfl_xor(mx, 2, 64));
            mx = fmaxf(mx, __shfl_xor(mx, 4, 64));
            mx = fmaxf(mx, __shfl_xor(mx, 8, 64));
            float mn = fmaxf(m_i[r], mx);
            alpha[r] = __expf(m_i[r] - mn);
            float sm = 0.f;
            #pragma unroll
            for (int kb = 0; kb < 4; ++kb) {
                float e = msk[kb] ? 0.f : __expf(vsc[kb] - mn);
                p[kb][r] = e;
                sm += e;
            }
            sm += __shfl_xor(sm, 1, 64);
            sm += __shfl_xor(sm, 2, 64);
            sm += __shfl_xor(sm, 4, 64);
            sm += __shfl_xor(sm, 8, 64);
            l_i[r] = l_i[r] * alpha[r] + sm;
            m_i[r] = mn;
        }

        __syncthreads();   // prev-iter PV reads of Vt complete

        // ---- write V transposed ----
        unsigned short vs[16];
        *(ushort4*)(vs + 0)  = v0; *(ushort4*)(vs + 4)  = v1;
        *(ushort4*)(vs + 8)  = v2; *(ushort4*)(vs + 12) = v3;
        #pragma unroll
        for (int i = 0; i < 16; ++i) Vt[vd + i][vkey] = vs[i];

        // ---- write P (private region, bf16) ----
        #pragma unroll
        for (int r = 0; r < 4; ++r)
            #pragma unroll
            for (int kb = 0; kb < 4; ++kb)
                Ps[w][lg * 4 + r][kb * 16 + ln] = f2bf(p[kb][r]);

        __syncthreads();   // Vt visible to all

        // ---- O = O*alpha + P @ V ----
        #pragma unroll
        for (int nb = 0; nb < 4; ++nb)
            #pragma unroll
            for (int r = 0; r < 4; ++r)
                O[nb][r] *= alpha[r];

        const unsigned short* pb = &Ps[w][ln][lg * 8];
        bf16x8 af0 = *(const bf16x8*)(pb);
        bf16x8 af1 = *(const bf16x8*)(pb + 32);
        #pragma unroll
        for (int nb = 0; nb < 4; ++nb) {
            const unsigned short* vp = &Vt[nb * 16 + ln][lg * 8];
            bf16x8 bf0 = *(const bf16x8*)(vp);
            bf16x8 bf1 = *(const bf16x8*)(vp + 32);
            O[nb] = __builtin_amdgcn_mfma_f32_16x16x32_bf16(af0, bf0, O[nb], 0, 0, 0);
            O[nb] = __builtin_amdgcn_mfma_f32_16x16x32_bf16(af1, bf1, O[nb], 0, 0, 0);
        }
    }

    // ---- epilogue: normalize, store head-concat bf16 ----
    unsigned short* ob = att + ((size_t)b * SEQ + row0 + w * 16) * DMODEL + h * DHEAD;
    #pragma unroll
    for (int r = 0; r < 4; ++r) {
        float inv = 1.0f / l_i[r];
        #pragma unroll
        for (int nb = 0; nb < 4; ++nb)
            ob[(size_t)(lg * 4 + r) * DMODEL + nb * 16 + ln] = f2bf(O[nb][r] * inv);
    }
}

extern "C" void kernel_launch(void* const* d_in, const int* in_sizes, int n_in,
                              void* d_out, int out_size, void* d_ws, size_t ws_size,
                              hipStream_t stream) {
    const float* q    = (const float*)d_in[0];
    const float* k    = (const float*)d_in[1];
    const float* v    = (const float*)d_in[2];
    const int*   mask = (const int*)  d_in[3];
    const float* Wq   = (const float*)d_in[4];
    const float* Wk   = (const float*)d_in[5];
    const float* Wv   = (const float*)d_in[6];
    const float* Wo   = (const float*)d_in[7];
    float* out = (float*)d_out;

    // ws layout (bf16 elems): qh | kh | vh | att | Wqt | Wkt | Wvt | Wot | mpack
    unsigned short* ws  = (unsigned short*)d_ws;
    const size_t n1 = (size_t)NB * NH * SEQ * DHEAD;      // 4,194,304
    const size_t nw = (size_t)NH * DHEAD * DMODEL;        // 1,048,576
    unsigned short* qh  = ws;
    unsigned short* kh  = qh + n1;
    unsigned short* vh  = kh + n1;
    unsigned short* att = vh + n1;
    unsigned short* Wqt = att + n1;
    unsigned short* Wkt = Wqt + nw;
    unsigned short* Wvt = Wkt + nw;
    unsigned short* Wot = Wvt + nw;
    unsigned long long* mpack = (unsigned long long*)(Wot + (size_t)DMODEL * DMODEL);

    pack_mask_kernel<<<dim3(NB * SEQ / 4), 256, 0, stream>>>(mask, mpack);
    transpose_cvt_kernel<<<dim3(1, 16, NH), 256, 0, stream>>>(Wq, Wqt, DMODEL, DHEAD);
    transpose_cvt_kernel<<<dim3(1, 16, NH), 256, 0, stream>>>(Wk, Wkt, DMODEL, DHEAD);
    transpose_cvt_kernel<<<dim3(1, 16, NH), 256, 0, stream>>>(Wv, Wvt, DMODEL, DHEAD);
    transpose_cvt_kernel<<<dim3(16, 16, 1), 256, 0, stream>>>(Wo, Wot, DMODEL, DMODEL);

    gemm_kernel<0><<<dim3(8, 32), 256, 0, stream>>>(q, Wqt, qh);
    gemm_kernel<0><<<dim3(8, 32), 256, 0, stream>>>(k, Wkt, kh);
    gemm_kernel<0><<<dim3(8, 32), 256, 0, stream>>>(v, Wvt, vh);

    attn_kernel<<<dim3(SEQ / 64, NB * NH), 256, 0, stream>>>(qh, kh, vh, mpack, att);

    gemm_kernel<1><<<dim3(8, 32), 256, 0, stream>>>(att, Wot, out);
}